// Round 1
// baseline (131.522 us; speedup 1.0000x reference)
//
#include <hip/hip_runtime.h>
#include <hip/hip_bf16.h>

#define C 336
#define CR 84
#define BB 256
#define HW 196            // 14*14
#define NTOT (BB*C*HW)    // 16859136

typedef __attribute__((ext_vector_type(8))) short bf16x8;
typedef __attribute__((ext_vector_type(4))) float f32x4;

__device__ __forceinline__ short f2bf(float f) {
    unsigned u = __builtin_bit_cast(unsigned, f);
    u += 0x7fffu + ((u >> 16) & 1u);   // round-to-nearest-even
    return (short)(u >> 16);
}

// ---------------------------------------------------------------- prep w53 -> bf16 frag-linear
// frag f = kc*21+nf; element layout: wbf[(f*64 + lane)*8 + j] = bf16(w53[o][c])
// o = nf*16 + (lane&15), c = kc*32 + (lane>>4)*8 + j   (zero-padded for c>=336)
__global__ void prep_w(const float* __restrict__ w53, short* __restrict__ wbf) {
    const int f = blockIdx.x;           // 0..230
    const int kc = f / 21, nf = f - kc * 21;
    const int lane = threadIdx.x;       // 0..63
    const int o = nf * 16 + (lane & 15);
    const int cb = kc * 32 + (lane >> 4) * 8;
    short* dst = wbf + ((size_t)f * 64 + lane) * 8;
#pragma unroll
    for (int j = 0; j < 8; ++j) {
        const int c = cb + j;
        const float w = (c < C) ? w53[o * C + c] : 0.f;
        dst[j] = f2bf(w);
    }
}

// ---------------------------------------------------------------- SE gate
__global__ void gate_kernel(const float* __restrict__ x160,
                            const float* __restrict__ w51, const float* __restrict__ b51,
                            const float* __restrict__ w52, const float* __restrict__ b52,
                            float* __restrict__ gate)
{
    __shared__ float s[C];
    __shared__ float h[CR];
    const int b = blockIdx.x, t = threadIdx.x;
    for (int c = t; c < C; c += blockDim.x) s[c] = x160[b * C + c];
    __syncthreads();
    if (t < CR) {
        float a = b51[t];
        const float* wr = w51 + t * C;
        for (int c = 0; c < C; ++c) a = fmaf(wr[c], s[c], a);
        h[t] = fmaxf(a, 0.f);
    }
    __syncthreads();
    for (int o = t; o < C; o += blockDim.x) {
        float a = b52[o];
        const float* wr = w52 + o * CR;
        for (int j = 0; j < CR; ++j) a = fmaf(wr[j], h[j], a);
        gate[b * C + o] = 1.f / (1.f + expf(-a));
    }
}

// ---------------------------------------------------------------- main GEMM (register-direct MFMA)
// out[b][o][p] = sum_c w53[o][c] * gate[b][c] * x159[b][c][p]
// M = 50176 rows (m = b*196+p), grid 784 blocks x 4 waves, wave owns 16 rows x 336 cols.
__global__ __launch_bounds__(256, 2) void gemm_kernel(
    const float* __restrict__ x159, const float* __restrict__ gate,
    const short* __restrict__ wbf, float* __restrict__ out)
{
    const int lane = threadIdx.x & 63;
    const int wid  = threadIdx.x >> 6;
    const int m0   = blockIdx.x * 64 + wid * 16;

    // A-load row for this lane (A frag: row = lane&15, k = (lane>>4)*8 + j)
    const int mA = m0 + (lane & 15);
    const int bA = mA / HW;
    const int pA = mA - bA * HW;
    const float* __restrict__ xrow = x159 + (size_t)bA * (C * HW) + pA;
    const float* __restrict__ grow = gate + bA * C;
    const int kg = lane >> 4;

    f32x4 acc[21];
#pragma unroll
    for (int i = 0; i < 21; ++i) acc[i] = f32x4{0.f, 0.f, 0.f, 0.f};

    for (int kc = 0; kc < 11; ++kc) {
        const int cbase = kc * 32 + kg * 8;
        bf16x8 afrag;
#pragma unroll
        for (int j = 0; j < 8; ++j) {
            const int c = cbase + j;
            float v = 0.f;
            if (c < C) v = xrow[(size_t)c * HW] * grow[c];
            afrag[j] = f2bf(v);
        }
        const short* __restrict__ wb = wbf + (size_t)kc * 21 * 512 + lane * 8;
#pragma unroll
        for (int nf = 0; nf < 21; ++nf) {
            const bf16x8 bfrag = *(const bf16x8*)(wb + (size_t)nf * 512);
            acc[nf] = __builtin_amdgcn_mfma_f32_16x16x32_bf16(afrag, bfrag, acc[nf], 0, 0, 0);
        }
    }

    // C write: lane holds rows mC..mC+3 (regs 0..3), col o = nf*16 + (lane&15).
    // 196 % 4 == 0 and mC % 4 == 0 -> 4-row group never straddles a batch boundary.
    const int mC = m0 + kg * 4;
    const int bC = mC / HW;
    const int pC = mC - bC * HW;
    float* __restrict__ obase = out + (size_t)bC * (C * HW) + pC;
    const int oc = lane & 15;
#pragma unroll
    for (int nf = 0; nf < 21; ++nf) {
        *(f32x4*)(obase + (size_t)(nf * 16 + oc) * HW) = acc[nf];
    }
}

// ---------------------------------------------------------------- BN stats, stage 1
// grid = 336*8, block 256: block (o,bg) sums 32 batches of channel o.
__global__ void stats_partial(const float* __restrict__ x166, float* __restrict__ part) {
    const int o = blockIdx.x >> 3;
    const int bg = blockIdx.x & 7;
    float s = 0.f, q = 0.f;
    for (int i = threadIdx.x; i < 32 * HW; i += 256) {
        const int bl = i / HW;
        const int p = i - bl * HW;
        const int b = (bg << 5) + bl;
        const float v = x166[((size_t)b * C + o) * HW + p];
        s += v; q += v * v;
    }
    __shared__ float rs[256], rq[256];
    rs[threadIdx.x] = s; rq[threadIdx.x] = q;
    __syncthreads();
    for (int st = 128; st > 0; st >>= 1) {
        if (threadIdx.x < st) {
            rs[threadIdx.x] += rs[threadIdx.x + st];
            rq[threadIdx.x] += rq[threadIdx.x + st];
        }
        __syncthreads();
    }
    if (threadIdx.x == 0) {
        part[blockIdx.x * 2]     = rs[0];
        part[blockIdx.x * 2 + 1] = rq[0];
    }
}

// ---------------------------------------------------------------- BN stats, stage 2
__global__ void stats_final(const float* __restrict__ part,
                            const float* __restrict__ gamma, const float* __restrict__ beta,
                            float* __restrict__ ab)
{
    const int o = threadIdx.x;
    if (o < C) {
        float s = 0.f, q = 0.f;
        for (int bg = 0; bg < 8; ++bg) {
            s += part[(o * 8 + bg) * 2];
            q += part[(o * 8 + bg) * 2 + 1];
        }
        const float invN = 1.f / (float)(BB * HW);
        const float mean = s * invN;
        const float var = fmaxf(q * invN - mean * mean, 0.f);
        const float rstd = rsqrtf(var + 1e-5f);
        const float a = rstd * gamma[o];
        ab[o * 2] = a;
        ab[o * 2 + 1] = beta[o] - mean * a;
    }
}

// ---------------------------------------------------------------- normalize in place
__global__ void norm_kernel(float* __restrict__ out, const float* __restrict__ ab) {
    const int i = blockIdx.x * 256 + threadIdx.x;   // float4 index; 196%4==0 -> never crosses channel
    const int base = i * 4;
    const int o = (base / HW) % C;
    const float a = ab[o * 2], b = ab[o * 2 + 1];
    f32x4 v = *(const f32x4*)(out + (size_t)base);
#pragma unroll
    for (int j = 0; j < 4; ++j) v[j] = fmaf(v[j], a, b);
    *(f32x4*)(out + (size_t)base) = v;
}

// ---------------------------------------------------------------- launch
extern "C" void kernel_launch(void* const* d_in, const int* in_sizes, int n_in,
                              void* d_out, int out_size, void* d_ws, size_t ws_size,
                              hipStream_t stream)
{
    const float* x160  = (const float*)d_in[0];
    const float* x159  = (const float*)d_in[1];
    const float* w51   = (const float*)d_in[2];
    const float* b51   = (const float*)d_in[3];
    const float* w52   = (const float*)d_in[4];
    const float* b52   = (const float*)d_in[5];
    const float* w53   = (const float*)d_in[6];
    const float* gamma = (const float*)d_in[7];
    const float* beta  = (const float*)d_in[8];
    float* out = (float*)d_out;

    // ws layout (total ~605 KB)
    char* ws = (char*)d_ws;
    float* gate = (float*)ws;                 // 86016 floats  (344064 B)
    short* wbf  = (short*)(ws + 344064);      // 118272 shorts (236544 B)
    float* part = (float*)(ws + 580608);      // 5376 floats   (21504 B)
    float* ab   = (float*)(ws + 602112);      // 672 floats

    hipLaunchKernelGGL(prep_w,        dim3(231),   dim3(64),  0, stream, w53, wbf);
    hipLaunchKernelGGL(gate_kernel,   dim3(BB),    dim3(128), 0, stream, x160, w51, b51, w52, b52, gate);
    hipLaunchKernelGGL(gemm_kernel,   dim3(784),   dim3(256), 0, stream, x159, gate, wbf, out);
    hipLaunchKernelGGL(stats_partial, dim3(C * 8), dim3(256), 0, stream, out, part);
    hipLaunchKernelGGL(stats_final,   dim3(1),     dim3(384), 0, stream, part, gamma, beta, ab);
    hipLaunchKernelGGL(norm_kernel,   dim3(16464), dim3(256), 0, stream, out, ab);
}